// Round 10
// baseline (465.924 us; speedup 1.0000x reference)
//
#include <hip/hip_runtime.h>

#define AS1 __attribute__((address_space(1)))
#define AS3 __attribute__((address_space(3)))

typedef __bf16 bf16_t;
typedef __bf16 bf16x8 __attribute__((ext_vector_type(8)));
typedef __bf16 bf16x4 __attribute__((ext_vector_type(4)));
typedef float  floatx4 __attribute__((ext_vector_type(4)));
typedef unsigned int uint2_ __attribute__((ext_vector_type(2)));
typedef unsigned int uint4_ __attribute__((ext_vector_type(4)));

#define MFMA_BF16(a, b, c) __builtin_amdgcn_mfma_f32_16x16x32_bf16(a, b, c, 0, 0, 0)

static constexpr int T_  = 2048;
static constexpr int D_  = 3584;
static constexpr int NH_ = 28;   // query heads
static constexpr int KV_ = 4;    // kv heads
static constexpr int H_  = 128;  // head dim
static constexpr int NW_ = 36;   // 28 q + 4 k + 4 v projection heads

// H^-0.5 * log2(e): softmax runs in the exp2 domain (R2/R3-verified numerics)
#define QSCALE 0.12754245778287616f

#define WAITV(n) asm volatile("s_waitcnt vmcnt(" #n ")" ::: "memory")

// ---------------------------------------------------------------------------
// Elementwise fp32 -> bf16 convert (8 elems/thread)
// ---------------------------------------------------------------------------
__global__ void convert_f32_bf16(const float* __restrict__ src, bf16_t* __restrict__ dst) {
    const long i = (long)(blockIdx.x * blockDim.x + threadIdx.x) * 8;
    float4 a = ((const float4*)(src + i))[0];
    float4 b = ((const float4*)(src + i))[1];
    bf16x8 o = {(bf16_t)a.x, (bf16_t)a.y, (bf16_t)a.z, (bf16_t)a.w,
                (bf16_t)b.x, (bf16_t)b.y, (bf16_t)b.z, (bf16_t)b.w};
    *(bf16x8*)(dst + i) = o;
}

// ---------------------------------------------------------------------------
// 64x64-tile fp32 -> bf16 transpose: dst[c][r] = (bf16)src[r][c].
// transpose_wqkv: all 36 qkv weight heads in ONE launch (pointer select on z).
// transpose64_f32_bf16: generic (used for wo).
// ---------------------------------------------------------------------------
__device__ __forceinline__ void tr64_body(const float* __restrict__ src, bf16_t* __restrict__ dst,
                                          int R, int C, int r0, int c0, int tid) {
    __shared__ bf16_t t[64][68];
#pragma unroll
    for (int p = 0; p < 4; p++) {
        const int row = (tid >> 4) + p * 16, col4 = tid & 15;
        float4 v = *(const float4*)(src + (long)(r0 + row) * C + c0 + col4 * 4);
        bf16x4 b = {(bf16_t)v.x, (bf16_t)v.y, (bf16_t)v.z, (bf16_t)v.w};
        *(bf16x4*)&t[row][col4 * 4] = b;
    }
    __syncthreads();
#pragma unroll
    for (int p = 0; p < 2; p++) {
        const int cc = (tid >> 3) + p * 32, k = tid & 7;
        bf16x8 o;
#pragma unroll
        for (int j = 0; j < 8; j++) o[j] = t[8 * k + j][cc];
        *(bf16x8*)(dst + (long)(c0 + cc) * R + r0 + 8 * k) = o;
    }
}

__global__ __launch_bounds__(256) void transpose64_f32_bf16(const float* __restrict__ src,
                                                            bf16_t* __restrict__ dst,
                                                            int R, int C, long sStride, long dStride) {
    tr64_body(src + (long)blockIdx.z * sStride, dst + (long)blockIdx.z * dStride,
              R, C, blockIdx.y * 64, blockIdx.x * 64, threadIdx.x);
}

__global__ __launch_bounds__(256) void transpose_wqkv(const float* __restrict__ wq,
                                                      const float* __restrict__ wk,
                                                      const float* __restrict__ wv,
                                                      bf16_t* __restrict__ dst) {
    const int z = blockIdx.z;
    const long whd = (long)D_ * H_;
    const float* src = z < NH_ ? wq + (long)z * whd
                               : (z < NH_ + KV_ ? wk + (long)(z - NH_) * whd
                                                : wv + (long)(z - NH_ - KV_) * whd);
    tr64_body(src, dst + (long)z * whd, D_, H_, blockIdx.y * 64, blockIdx.x * 64, threadIdx.x);
}

// ---------------------------------------------------------------------------
// R10 GEMM: R9-verified ring-3 / WAITV(4) / swizzle / setprio core, plus:
//  * 2D XCD supertile: XCD x owns an 8 x NTX rectangle of (mt,nt) -> per-XCD
//    B-panel footprint 36 -> 9 panels (R9 counters: FETCH 216 MB = every XCD
//    streaming ALL of B; the 1D chunk map was the cause).
//  * QKV epilogue fuses RoPE (LDS partner-exchange, fp32 self) and writes V
//    heads transposed straight to vT -> rope_kernel + transpose32 deleted.
// ---------------------------------------------------------------------------
__device__ __forceinline__ void stage_t128(const bf16_t* __restrict__ g, int kt,
                                           bf16_t* sl, int tid) {
#pragma unroll
    for (int c = 0; c < 2; c++) {
        const int chunk = c * 256 + tid;      // 512 chunks: 128 rows x 4
        const int pair = chunk >> 3, P = chunk & 7;
        const int L = P ^ (pair & 7);
        const int row = (pair << 1) | (L >> 2);
        const int cc = L & 3;
        __builtin_amdgcn_global_load_lds((const AS1 void*)(g + (long)row * D_ + kt + cc * 8),
                                         (AS3 void*)(sl + chunk * 8), 16, 0, 0);
    }
}

__device__ __forceinline__ void gstep(const bf16_t* __restrict__ As, const bf16_t* __restrict__ Bs,
                                      bf16_t* Asn, bf16_t* Bsn,
                                      const bf16_t* __restrict__ Ag, const bf16_t* __restrict__ Bg,
                                      int ktn, bool do_stage, int tid,
                                      int wr, int wn, int m16, int quad,
                                      floatx4 acc[4][4]) {
    bf16x8 af[4], bfv[4];
#pragma unroll
    for (int i = 0; i < 4; i++) {
        const int rr = wr * 64 + i * 16 + m16;
        const int L = ((rr & 1) << 2) | quad;
        af[i] = *(const bf16x8*)(As + ((rr >> 1) << 6) + ((L ^ ((rr >> 1) & 7)) << 3));
    }
#pragma unroll
    for (int j = 0; j < 4; j++) {
        const int rr = wn * 64 + j * 16 + m16;
        const int L = ((rr & 1) << 2) | quad;
        bfv[j] = *(const bf16x8*)(Bs + ((rr >> 1) << 6) + ((L ^ ((rr >> 1) & 7)) << 3));
    }
    if (do_stage) {
        stage_t128(Ag, ktn, Asn, tid);
        stage_t128(Bg, ktn, Bsn, tid);
    }
    __builtin_amdgcn_s_setprio(1);
#pragma unroll
    for (int i = 0; i < 4; i++)
#pragma unroll
        for (int j = 0; j < 4; j++) acc[i][j] = MFMA_BF16(af[i], bfv[j], acc[i][j]);
    __builtin_amdgcn_s_setprio(0);
}

#define GSTEP(AS_, BS_, ASN_, BSN_, STG_)                                         \
    WAITV(4); __builtin_amdgcn_s_barrier();                                       \
    gstep(AS_, BS_, ASN_, BSN_, Ag, Bg, kts, STG_, tid, wr, wn, m16, quad, acc);  \
    kts += 32;

template<bool QKV>
__global__ __launch_bounds__(256, 3) void gemm128_kernel(const bf16_t* __restrict__ A,
                                                         const bf16_t* __restrict__ Bt,
                                                         const float* __restrict__ bq,
                                                         const float* __restrict__ bk,
                                                         const float* __restrict__ bv,
                                                         const int* __restrict__ pos,
                                                         bf16_t* __restrict__ outb,
                                                         bf16_t* __restrict__ vTout,
                                                         float* __restrict__ outf,
                                                         int NTX) {
    __shared__ bf16_t SM[24576];                  // 48 KB: ring (6 x 4096) / rope exchange
    bf16_t* As0 = SM;
    bf16_t* As1 = SM + 4096;
    bf16_t* As2 = SM + 8192;
    bf16_t* Bs0 = SM + 12288;
    bf16_t* Bs1 = SM + 16384;
    bf16_t* Bs2 = SM + 20480;

    // 2D XCD supertile: XCD = lin&7 owns rows (x&1)*8..+7, cols (x>>1)*NTX..+NTX-1
    const int x = blockIdx.x & 7;
    const int k = blockIdx.x >> 3;
    const int mt = (x & 1) * 8 + (k & 7);
    const int nt = (x >> 1) * NTX + (k >> 3);

    const bf16_t* Ag = A + (long)mt * 128 * D_;
    const bf16_t* Bg = Bt + (long)nt * 128 * D_;

    const int tid = threadIdx.x, w = tid >> 6, l = tid & 63;
    const int m16 = l & 15, quad = l >> 4;
    const int wr = w >> 1, wn = w & 1;

    floatx4 acc[4][4];
#pragma unroll
    for (int i = 0; i < 4; i++)
#pragma unroll
        for (int j = 0; j < 4; j++) acc[i][j] = (floatx4){0.f, 0.f, 0.f, 0.f};

    stage_t128(Ag, 0, As0, tid);  stage_t128(Bg, 0, Bs0, tid);
    stage_t128(Ag, 32, As1, tid); stage_t128(Bg, 32, Bs1, tid);
    int kts = 64;

#pragma unroll 1
    for (int g = 0; g < 36; g++) {                 // s = 0..107
        GSTEP(As0, Bs0, As2, Bs2, true)
        GSTEP(As1, Bs1, As0, Bs0, true)
        GSTEP(As2, Bs2, As1, Bs1, true)
    }
    GSTEP(As0, Bs0, As2, Bs2, true)                // s=108
    GSTEP(As1, Bs1, As0, Bs0, true)                // s=109
    WAITV(4); __builtin_amdgcn_s_barrier();
    gstep(As2, Bs2, As0, Bs0, Ag, Bg, 0, false, tid, wr, wn, m16, quad, acc);   // s=110
    WAITV(0); __builtin_amdgcn_s_barrier();
    gstep(As0, Bs0, As1, Bs1, Ag, Bg, 0, false, tid, wr, wn, m16, quad, acc);   // s=111

    if (QKV) {
        const int hd = nt;
        const float* bias = hd < NH_ ? bq + hd * H_
                                     : (hd < NH_ + KV_ ? bk + (hd - NH_) * H_
                                                       : bv + (hd - NH_ - KV_) * H_);
        if (hd >= NH_ + KV_) {
            // V head: no rope; write transposed straight to vT[kvh][h][t]
            bf16_t* Vt = vTout + (long)(hd - NH_ - KV_) * H_ * T_;
#pragma unroll
            for (int j = 0; j < 4; j++) {
                const int col = wn * 64 + j * 16 + m16;
                const float bb = bias[col];
#pragma unroll
                for (int i = 0; i < 4; i++) {
                    const int grow = mt * 128 + wr * 64 + i * 16 + quad * 4;
                    bf16x4 v = {(bf16_t)(acc[i][j][0] + bb), (bf16_t)(acc[i][j][1] + bb),
                                (bf16_t)(acc[i][j][2] + bb), (bf16_t)(acc[i][j][3] + bb)};
                    *(bf16x4*)(Vt + (long)col * T_ + grow) = v;
                }
            }
        } else {
            // q/k head: partner-exchange via LDS (stride 132 kills bank aliasing),
            // rotate with fp32 self + bf16 partner, scale q by QSCALE.
            __syncthreads();                      // ring reads done before overwrite
#pragma unroll
            for (int j = 0; j < 4; j++) {
                const int col = wn * 64 + j * 16 + m16;
                const float bb = bias[col];
#pragma unroll
                for (int i = 0; i < 4; i++) {
                    const int lr = wr * 64 + i * 16 + quad * 4;
#pragma unroll
                    for (int r = 0; r < 4; r++)
                        SM[(lr + r) * 132 + col] = (bf16_t)(acc[i][j][r] + bb);
                }
            }
            __syncthreads();
            bf16_t* C = outb + (long)hd * T_ * H_ + (long)(mt * 128) * H_;
#pragma unroll
            for (int j = 0; j < 4; j++) {
                const int col = wn * 64 + j * 16 + m16;
                const float bb = bias[col];
                const int h = col & 63;
                const float inv = expf(-(float)h * (13.815510557964274f / 64.f));
                const float sgn = (col < 64) ? -1.f : 1.f;
#pragma unroll
                for (int i = 0; i < 4; i++) {
                    const int lr = wr * 64 + i * 16 + quad * 4;
#pragma unroll
                    for (int r = 0; r < 4; r++) {
                        const int row = lr + r;
                        const float self = acc[i][j][r] + bb;
                        const float partner = (float)SM[row * 132 + (col ^ 64)];
                        const float ang = (float)pos[mt * 128 + row] * inv;
                        float s, c;
                        sincosf(ang, &s, &c);
                        float o = self * c + sgn * partner * s;
                        if (hd < NH_) o *= QSCALE;
                        C[(long)row * H_ + col] = (bf16_t)o;
                    }
                }
            }
        }
    } else {
        float* C = outf + (long)(mt * 128) * D_ + nt * 128;
#pragma unroll
        for (int j = 0; j < 4; j++) {
            const int col = wn * 64 + j * 16 + m16;
#pragma unroll
            for (int i = 0; i < 4; i++) {
                const int row = wr * 64 + i * 16 + quad * 4;
#pragma unroll
                for (int r = 0; r < 4; r++) C[(long)(row + r) * D_ + col] = acc[i][j][r];
            }
        }
    }
}

// ---------------------------------------------------------------------------
// R9 flash attention (verified): 448 blocks, 8 waves x 16 rows, LPT order,
// double-buffered gload_lds staging, exp2 softmax + defer-max. Unchanged.
// ---------------------------------------------------------------------------
__device__ __forceinline__ void attn_stage9(const bf16_t* __restrict__ Kg,
                                            const bf16_t* __restrict__ Vg,
                                            int sb, int tid,
                                            const int kOff[2], const int vOff[2],
                                            bf16_t* Ks, bf16_t* Vs) {
    const long kBase = (long)sb * 64 * H_;
    const int  vBase = sb * 64;
#pragma unroll
    for (int i = 0; i < 2; i++)
        __builtin_amdgcn_global_load_lds((const AS1 void*)(Kg + kBase + kOff[i]),
                                         (AS3 void*)(Ks + (i * 512 + tid) * 8), 16, 0, 0);
#pragma unroll
    for (int i = 0; i < 2; i++)
        __builtin_amdgcn_global_load_lds((const AS1 void*)(Vg + vBase + vOff[i]),
                                         (AS3 void*)(Vs + (i * 512 + tid) * 8), 16, 0, 0);
}

__device__ __forceinline__ void attn_step9(const bf16_t* __restrict__ Ks,
                                           const bf16_t* __restrict__ Vs,
                                           int sb, int q0, int m16, int quad,
                                           int s0, int s1, bool hiq,
                                           const bf16x8 qf[4], floatx4 ot[8],
                                           float& mi, float& li) {
    floatx4 stv[4];
    __builtin_amdgcn_s_setprio(1);
#pragma unroll
    for (int ts = 0; ts < 4; ts++) {
        bf16x8 kf[4];
#pragma unroll
        for (int kk = 0; kk < 4; kk++)
            kf[kk] = *(const bf16x8*)(Ks + (16 * ts + m16) * 128 +
                                      ((((kk << 2) + quad) ^ (m16 & 7)) << 3));
        floatx4 c = (floatx4){0.f, 0.f, 0.f, 0.f};
#pragma unroll
        for (int kk = 0; kk < 4; kk++) c = MFMA_BF16(kf[kk], qf[kk], c);
        stv[ts] = c;
    }
    __builtin_amdgcn_s_setprio(0);

    unsigned int W[4][2];
    const int qg = q0 + m16;
    if ((sb * 64 + 63) > q0) {
#pragma unroll
        for (int ts = 0; ts < 4; ts++)
#pragma unroll
            for (int r = 0; r < 4; r++) {
                const int sg = sb * 64 + ts * 16 + quad * 4 + r;
                if (sg > qg) stv[ts][r] = -1e30f;
            }
    }
    float mx = -1e30f;
#pragma unroll
    for (int ts = 0; ts < 4; ts++)
#pragma unroll
        for (int r = 0; r < 4; r++) mx = fmaxf(mx, stv[ts][r]);
    mx = fmaxf(mx, __shfl_xor(mx, 16));
    mx = fmaxf(mx, __shfl_xor(mx, 32));
    float mn = mi;
    if (__any(mx > mi + 8.f)) {                  // defer-max (T13)
        mn = fmaxf(mi, mx);
        const float alpha = exp2f(mi - mn);
        mi = mn;
        li *= alpha;
#pragma unroll
        for (int ht = 0; ht < 8; ht++) ot[ht] *= alpha;
    }
    float rs = 0.f;
#pragma unroll
    for (int ts = 0; ts < 4; ts++) {
        const float p0 = exp2f(stv[ts][0] - mn);
        const float p1 = exp2f(stv[ts][1] - mn);
        const float p2 = exp2f(stv[ts][2] - mn);
        const float p3 = exp2f(stv[ts][3] - mn);
        rs += p0 + p1 + p2 + p3;
        bf16x4 pv = {(bf16_t)p0, (bf16_t)p1, (bf16_t)p2, (bf16_t)p3};
        uint2_ u = __builtin_bit_cast(uint2_, pv);
        W[ts][0] = u.x;
        W[ts][1] = u.y;
    }
    rs += __shfl_xor(rs, 16);
    rs += __shfl_xor(rs, 32);
    li += rs;

#pragma unroll
    for (int ck = 0; ck < 2; ck++) {
        const unsigned a0 = W[2 * ck][0], a1 = W[2 * ck][1];
        const unsigned b0 = W[2 * ck + 1][0], b1 = W[2 * ck + 1][1];
        unsigned pw0, pw1, pw2, pw3;
        { const unsigned xa = __shfl((int)a0, s0), xb = __shfl((int)b0, s0); pw0 = hiq ? xb : xa; }
        { const unsigned xa = __shfl((int)a1, s0), xb = __shfl((int)b1, s0); pw1 = hiq ? xb : xa; }
        { const unsigned xa = __shfl((int)a0, s1), xb = __shfl((int)b0, s1); pw2 = hiq ? xb : xa; }
        { const unsigned xa = __shfl((int)a1, s1), xb = __shfl((int)b1, s1); pw3 = hiq ? xb : xa; }
        uint4_ pv4 = {pw0, pw1, pw2, pw3};
        const bf16x8 pf = __builtin_bit_cast(bf16x8, pv4);
        __builtin_amdgcn_s_setprio(1);
#pragma unroll
        for (int ht = 0; ht < 8; ht++) {
            bf16x8 vf = *(const bf16x8*)(Vs + (16 * ht + m16) * 64 +
                                         ((((ck << 2) + quad) ^ (m16 & 7)) << 3));
            ot[ht] = MFMA_BF16(vf, pf, ot[ht]);
        }
        __builtin_amdgcn_s_setprio(0);
    }
}

__global__ __launch_bounds__(512) void attn_kernel(const bf16_t* __restrict__ qkv,
                                                   const bf16_t* __restrict__ vT,
                                                   bf16_t* __restrict__ ctx) {
    __shared__ bf16_t smem[32768];               // K0|K1|V0|V1, 16 KB each = 64 KB
    bf16_t* K0 = smem;
    bf16_t* K1 = smem + 8192;
    bf16_t* V0 = smem + 16384;
    bf16_t* V1 = smem + 24576;

    const int b = blockIdx.x;
    const int jt = 15 - (b / NH_);               // LPT: longest q-tiles dispatch first
    const int n  = b % NH_;
    const int kvh = n / 7;
    const bf16_t* Q  = qkv + (long)n * T_ * H_;
    const bf16_t* Kg = qkv + (long)(NH_ + kvh) * T_ * H_;
    const bf16_t* Vg = vT + (long)kvh * H_ * T_;   // [h][t]

    const int tid = threadIdx.x, w = tid >> 6, l = tid & 63;
    const int m16 = l & 15, quad = l >> 4;
    const int q0 = jt * 128 + w * 16;            // this wave's 16 rows

    int kOff[2], vOff[2];
#pragma unroll
    for (int i = 0; i < 2; i++) {
        const int ck_ = i * 512 + tid;           // K: 64 rows x 16 chunks = 1024
        const int kr = ck_ >> 4, kc = ck_ & 15;
        kOff[i] = kr * H_ + ((kc ^ (kr & 7)) << 3);
        const int vr = ck_ >> 3, vc = ck_ & 7;   // V: 128 rows x 8 chunks = 1024
        vOff[i] = vr * T_ + ((vc ^ (vr & 7)) << 3);
    }

    bf16x8 qf[4];
#pragma unroll
    for (int kk = 0; kk < 4; kk++)
        qf[kk] = *(const bf16x8*)(Q + (long)(q0 + m16) * H_ + kk * 32 + quad * 8);

    floatx4 ot[8];
#pragma unroll
    for (int ht = 0; ht < 8; ht++) ot[ht] = (floatx4){0.f, 0.f, 0.f, 0.f};
    float mi = -1e30f, li = 0.f;

    const int s0 = m16 + ((quad & 1) << 5);
    const int s1 = s0 + 16;
    const bool hiq = (quad & 2) != 0;

    const int E = 2 * jt + 2;                    // block-uniform trip count
    const int sbEw = (q0 + 79) >> 6;             // this wave's causal end

    attn_stage9(Kg, Vg, 0, tid, kOff, vOff, K0, V0);
    int sb = 0;
    while (true) {
        __syncthreads();
        if (sb + 1 < E) attn_stage9(Kg, Vg, sb + 1, tid, kOff, vOff, K1, V1);
        if (sb < sbEw) attn_step9(K0, V0, sb, q0, m16, quad, s0, s1, hiq, qf, ot, mi, li);
        if (++sb >= E) break;
        __syncthreads();
        if (sb + 1 < E) attn_stage9(Kg, Vg, sb + 1, tid, kOff, vOff, K0, V0);
        if (sb < sbEw) attn_step9(K1, V1, sb, q0, m16, quad, s0, s1, hiq, qf, ot, mi, li);
        if (++sb >= E) break;
    }
    __syncthreads();

    const float inv = 1.f / li;
    bf16_t* Oq = smem + w * 2048;
    {
        const int r = m16;
#pragma unroll
        for (int ht = 0; ht < 8; ht++) {
            bf16x4 v = {(bf16_t)(ot[ht][0] * inv), (bf16_t)(ot[ht][1] * inv),
                        (bf16_t)(ot[ht][2] * inv), (bf16_t)(ot[ht][3] * inv)};
            const int chunk = (2 * ht + (quad >> 1)) ^ (r & 7);
            *(bf16x4*)((char*)Oq + r * 256 + (chunk << 4) + ((quad & 1) << 3)) = v;
        }
    }
    {
        const int qrow = l >> 2, q4 = l & 3;
        bf16_t* dst = ctx + (long)(q0 + qrow) * (NH_ * H_) + n * H_ + q4 * 32;
#pragma unroll
        for (int j = 0; j < 4; j++) {
            const int chunk = (q4 * 4 + j) ^ (qrow & 7);
            const bf16x8 o = *(const bf16x8*)((char*)Oq + qrow * 256 + (chunk << 4));
            *(bf16x8*)(dst + j * 8) = o;
        }
    }
}

// ---------------------------------------------------------------------------
extern "C" void kernel_launch(void* const* d_in, const int* in_sizes, int n_in,
                              void* d_out, int out_size, void* d_ws, size_t ws_size,
                              hipStream_t stream) {
    const float* x  = (const float*)d_in[0];
    const int*   ps = (const int*)d_in[1];
    const float* wq = (const float*)d_in[2];
    const float* bq = (const float*)d_in[3];
    const float* wk = (const float*)d_in[4];
    const float* bk = (const float*)d_in[5];
    const float* wv = (const float*)d_in[6];
    const float* bv = (const float*)d_in[7];
    const float* wo = (const float*)d_in[8];
    float* out = (float*)d_out;

    bf16_t* xb  = (bf16_t*)d_ws;                 // [2048][3584]    x in bf16
    bf16_t* wt  = xb + (long)T_ * D_;            // [36][128][3584] transposed qkv weights
    bf16_t* woT = wt + (long)NW_ * H_ * D_;      // [3584][3584]    woT[d][n*H+h]
    bf16_t* qkv = woT + (long)D_ * D_;           // [36][2048][128] projections (V heads unused)
    bf16_t* vT  = qkv + (long)NW_ * T_ * H_;     // [4][128][2048]  V transposed (written by gemm)
    bf16_t* ctx = vT + (long)KV_ * H_ * T_;      // [2048][3584]    attention output (bf16)

    convert_f32_bf16<<<((long)T_ * D_ / 8 + 255) / 256, 256, 0, stream>>>(x, xb);
    transpose_wqkv<<<dim3(H_ / 64, D_ / 64, NW_), 256, 0, stream>>>(wq, wk, wv, wt);
    transpose64_f32_bf16<<<dim3(D_ / 64, D_ / 64, 1), 256, 0, stream>>>(wo, woT, D_, D_, 0, 0);

    gemm128_kernel<true><<<dim3(T_ / 128 * NW_), 256, 0, stream>>>(xb, wt, bq, bk, bv, ps,
                                                                   qkv, vT, nullptr, NW_ / 4);
    attn_kernel<<<dim3(16 * NH_), 512, 0, stream>>>(qkv, vT, ctx);
    gemm128_kernel<false><<<dim3(T_ / 128 * (D_ / 128)), 256, 0, stream>>>(ctx, woT, nullptr, nullptr, nullptr,
                                                                           nullptr, nullptr, nullptr, out,
                                                                           (D_ / 128) / 4);
}